// Round 12
// baseline (324.761 us; speedup 1.0000x reference)
//
#include <hip/hip_runtime.h>
#include <math.h>

#define NTOK   32768
#define DIM    2048
#define NE     256
#define NG     8
#define GSZ    32
#define NLIM   4
#define TOPK   8
#define RSCALE 2.5f
#define TAU    4e-7f

#define BT      32
#define THREADS 256
#define KT      16
#define NKT     (DIM / KT)        // 128
#define WOFF    262144            // wt at d_ws + 256 KB
#define TILE_B  16384             // one wt k-tile: [plane][khalf][256e]*16B

typedef __bf16 bf16x8 __attribute__((ext_vector_type(8)));
typedef float  f32x16 __attribute__((ext_vector_type(16)));

// ---------------------------------------------------------------------------
// Prekernel: split w1 into 2 bf16 planes, layout per 16-k tile (16 KB):
// cell g = ((kt*2+p)*2+hi)*256+e holds w1[e][kt*16+hi*8 .. +8), plane p.
// ---------------------------------------------------------------------------
__global__ __launch_bounds__(256) void wsplit_kernel(
    const float* __restrict__ w1, unsigned int* __restrict__ wt)
{
    const int g  = blockIdx.x * 256 + threadIdx.x;    // [0, 131072)
    const int e  = g & 255;
    const int hi = (g >> 8) & 1;
    const int p  = (g >> 9) & 1;
    const int kt = g >> 10;
    const float* src = w1 + (size_t)e * DIM + kt * 16 + hi * 8;

    uint4 o;
    unsigned int w[4];
#pragma unroll
    for (int q = 0; q < 4; ++q) {
        const float v0 = src[2 * q], v1 = src[2 * q + 1];
        const unsigned int u0 = __float_as_uint(v0);
        const unsigned int u1 = __float_as_uint(v1);
        if (p == 0) {
            w[q] = (u0 >> 16) | (u1 & 0xFFFF0000u);
        } else {
            const float r0 = v0 - __uint_as_float(u0 & 0xFFFF0000u);
            const float r1 = v1 - __uint_as_float(u1 & 0xFFFF0000u);
            w[q] = (__float_as_uint(r0) >> 16) |
                   (__float_as_uint(r1) & 0xFFFF0000u);
        }
    }
    o.x = w[0]; o.y = w[1]; o.z = w[2]; o.w = w[3];
    *(uint4*)(wt + (size_t)g * 4) = o;
}

// 2-plane truncation split of 8 f32 -> h-plane bf16x8 + r-plane bf16x8
__device__ __forceinline__ void split_pack(float4 a, float4 b,
                                           bf16x8& h8, bf16x8& r8) {
    float v[8] = {a.x, a.y, a.z, a.w, b.x, b.y, b.z, b.w};
    union { unsigned int u[4]; bf16x8 v8; } H, R;
#pragma unroll
    for (int q = 0; q < 4; ++q) {
        const unsigned int u0 = __float_as_uint(v[2 * q]);
        const unsigned int u1 = __float_as_uint(v[2 * q + 1]);
        H.u[q] = (u0 >> 16) | (u1 & 0xFFFF0000u);
        const float r0 = v[2 * q]     - __uint_as_float(u0 & 0xFFFF0000u);
        const float r1 = v[2 * q + 1] - __uint_as_float(u1 & 0xFFFF0000u);
        R.u[q] = (__float_as_uint(r0) >> 16) |
                 (__float_as_uint(r1) & 0xFFFF0000u);
    }
    h8 = H.v8; r8 = R.v8;
}

// ---------------------------------------------------------------------------
// Pass 1: 2-plane / 3-pass bf16 MFMA GEMM. 32 tok x 256 exp per block,
// 4 waves, grid 1024 => 4 blocks/CU.
// PURE DATAFLOW K-loop: A and B both global->register, split in VALU,
// zero LDS ops, zero barriers, zero inline asm. The compiler pipelines;
// 16 independent waves/CU provide the latency hiding (m114 TLP).
// ---------------------------------------------------------------------------
__global__ __launch_bounds__(THREADS, 4) void router_pass1(
    const float* __restrict__ x, const unsigned int* __restrict__ wt,
    const float* __restrict__ b_lin, const float* __restrict__ bias,
    float* __restrict__ out_vals, float* __restrict__ out_idx,
    int* __restrict__ wsI)
{
    __shared__ float sc[32 * 260];     // 33.3 KB logits (epilogue only)

    const int tid  = threadIdx.x;
    const int lane = tid & 63;
    const int wn   = tid >> 6;        // wave = expert quarter (0..3)
    const int l31  = lane & 31;
    const int hi   = lane >> 5;
    const int t0   = blockIdx.x * BT;

    // A: this lane's token row; 8 floats at k = kt*16 + hi*8
    const float4* xA = (const float4*)(x + (size_t)(t0 + l31) * DIM) + hi * 2;
    // B: e = wn*64 + ni*32 + l31, k-half hi, plane p
    const char* wb = (const char*)wt + hi * 4096 + (wn * 64 + l31) * 16;

    f32x16 acc[2] = {};

#pragma unroll 4
    for (int kt = 0; kt < NKT; ++kt) {
        const float4 f0 = xA[kt * 4];
        const float4 f1 = xA[kt * 4 + 1];
        const char* pB = wb + (size_t)kt * TILE_B;
        const bf16x8 b0h = *(const bf16x8*)(pB);
        const bf16x8 b0r = *(const bf16x8*)(pB + 8192);
        const bf16x8 b1h = *(const bf16x8*)(pB + 512);
        const bf16x8 b1r = *(const bf16x8*)(pB + 512 + 8192);
        bf16x8 ah, ar;
        split_pack(f0, f1, ah, ar);
        acc[0] = __builtin_amdgcn_mfma_f32_32x32x16_bf16(ah, b0h, acc[0], 0, 0, 0);
        acc[0] = __builtin_amdgcn_mfma_f32_32x32x16_bf16(ah, b0r, acc[0], 0, 0, 0);
        acc[0] = __builtin_amdgcn_mfma_f32_32x32x16_bf16(ar, b0h, acc[0], 0, 0, 0);
        acc[1] = __builtin_amdgcn_mfma_f32_32x32x16_bf16(ah, b1h, acc[1], 0, 0, 0);
        acc[1] = __builtin_amdgcn_mfma_f32_32x32x16_bf16(ah, b1r, acc[1], 0, 0, 0);
        acc[1] = __builtin_amdgcn_mfma_f32_32x32x16_bf16(ar, b1h, acc[1], 0, 0, 0);
    }

    // ---- routing epilogue: 32 tokens ----
#pragma unroll
    for (int ni = 0; ni < 2; ++ni) {
#pragma unroll
        for (int r = 0; r < 16; ++r) {
            const int row = (r & 3) + 8 * (r >> 2) + 4 * hi;
            const int e   = wn * 64 + ni * 32 + l31;
            sc[row * 260 + e] = acc[ni][r];
        }
    }
    __syncthreads();

    const int tx = tid & 31;
    const int ty = tid >> 5;          // 0..7
    float blv[8], bsv[8];
#pragma unroll
    for (int j = 0; j < 8; ++j) {
        blv[j] = b_lin[tx + 32 * j];
        bsv[j] = bias[tx + 32 * j];
    }

#pragma unroll
    for (int i = 0; i < 4; ++i) {
        const int row = ty * 4 + i;
        float s8[8];
        float psum = 0.0f;
#pragma unroll
        for (int j = 0; j < 8; ++j) {
            const float lg = sc[row * 260 + tx + 32 * j] + blv[j];
            const float s = 1.0f / (1.0f + expf(-lg));
            s8[j] = s;
            psum += s;
        }
#pragma unroll
        for (int m = 1; m <= 16; m <<= 1) psum += __shfl_xor(psum, m);
#pragma unroll
        for (int j = 0; j < 8; ++j) s8[j] = s8[j] / psum + bsv[j];

        float gm[8];
#pragma unroll
        for (int j = 0; j < 8; ++j) gm[j] = s8[j];
#pragma unroll
        for (int m = 1; m <= 16; m <<= 1)
#pragma unroll
            for (int j = 0; j < 8; ++j)
                gm[j] = fmaxf(gm[j], __shfl_xor(gm[j], m));

        unsigned keep = 0u;
        float g4v = 0.0f, g5v = 0.0f;
#pragma unroll
        for (int r = 0; r < 5; ++r) {
            float bv = -1e30f; int bg = 0;
#pragma unroll
            for (int g = 0; g < 8; ++g)
                if (!((keep >> g) & 1) && gm[g] > bv) { bv = gm[g]; bg = g; }
            if (r < 4) { keep |= 1u << bg; g4v = bv; }
            else g5v = bv;
        }
        float margin = g4v - g5v;

#pragma unroll
        for (int j = 0; j < 8; ++j)
            if (!((keep >> j) & 1)) s8[j] = -1e30f;

        float tv[9]; int te[9];
#pragma unroll
        for (int r = 0; r < 9; ++r) {
            float bv = -1e30f; int bj = 8;
#pragma unroll
            for (int j = 0; j < 8; ++j)
                if (s8[j] > bv) { bv = s8[j]; bj = j; }
            int be = (bj < 8) ? (tx + 32 * bj) : 9999;
#pragma unroll
            for (int m = 1; m <= 16; m <<= 1) {
                const float ov = __shfl_xor(bv, m);
                const int   oe = __shfl_xor(be, m);
                if (ov > bv || (ov == bv && oe < be)) { bv = ov; be = oe; }
            }
            tv[r] = bv; te[r] = be;
            if (r < 8 && (be & 31) == tx) s8[be >> 5] = -1e30f;
        }
#pragma unroll
        for (int r = 0; r < 8; ++r) margin = fminf(margin, tv[r] - tv[r + 1]);

        if (tx == 0) {
            const int t = t0 + row;
            const int base = t * TOPK;
#pragma unroll
            for (int r = 0; r < 8; ++r) {
                out_vals[base + r] = tv[r] * RSCALE;
                out_idx[base + r]  = (float)te[r];
            }
            if (margin < TAU) {
                const int slot = atomicAdd(&wsI[0], 1);
                if (slot < 60000) wsI[4 + slot] = t;
            }
        }
    }
}

// ---------------------------------------------------------------------------
// Pass 2: exact fp64 recompute + reroute for margin-flagged tokens.
// ---------------------------------------------------------------------------
__global__ __launch_bounds__(256, 1) void router_pass2(
    const float* __restrict__ x, const float* __restrict__ w1,
    const float* __restrict__ b_lin, const float* __restrict__ bias,
    float* __restrict__ out_vals, float* __restrict__ out_idx,
    const int* __restrict__ wsI)
{
    __shared__ double xrow[DIM];
    __shared__ double red[256];
    __shared__ double sc[NE];

    const int tid = threadIdx.x;
    const int count = min(wsI[0], 60000);
    const int* list = wsI + 4;
    const float4* x4 = (const float4*)x;
    const float4* w4 = (const float4*)w1;

    for (int li = blockIdx.x; li < count; li += gridDim.x) {
        const int t = list[li];
        __syncthreads();
#pragma unroll
        for (int q = 0; q < 2; ++q) {
            const int id = tid + 256 * q;
            const float4 v = x4[t * 512 + id];
            xrow[id * 4 + 0] = (double)v.x;
            xrow[id * 4 + 1] = (double)v.y;
            xrow[id * 4 + 2] = (double)v.z;
            xrow[id * 4 + 3] = (double)v.w;
        }
        __syncthreads();

        const int e = tid;
        double a0 = 0.0, a1 = 0.0, a2 = 0.0, a3 = 0.0;
#pragma unroll 2
        for (int k4 = 0; k4 < 512; k4 += 4) {
#pragma unroll
            for (int z = 0; z < 4; ++z) {
                const float4 wv = w4[e * 512 + k4 + z];
                double* ac = (z == 0) ? &a0 : (z == 1) ? &a1 : (z == 2) ? &a2 : &a3;
                *ac = fma(xrow[(k4 + z) * 4 + 0], (double)wv.x, *ac);
                *ac = fma(xrow[(k4 + z) * 4 + 1], (double)wv.y, *ac);
                *ac = fma(xrow[(k4 + z) * 4 + 2], (double)wv.z, *ac);
                *ac = fma(xrow[(k4 + z) * 4 + 3], (double)wv.w, *ac);
            }
        }
        const double lg = ((a0 + a1) + (a2 + a3)) + (double)b_lin[e];
        const double s = 1.0 / (1.0 + exp(-lg));
        red[tid] = s;
        __syncthreads();
        for (int off = 128; off > 0; off >>= 1) {
            if (tid < off) red[tid] += red[tid + off];
            __syncthreads();
        }
        sc[e] = s / red[0] + (double)bias[e];
        __syncthreads();

        if (tid == 0) {
            double gmax[NG];
            for (int g = 0; g < NG; ++g) {
                double mx = -INFINITY;
                for (int q = 0; q < GSZ; ++q) {
                    const double v = sc[g * GSZ + q];
                    mx = (v > mx) ? v : mx;
                }
                gmax[g] = mx;
            }
            unsigned keep = 0u;
            for (int r = 0; r < NLIM; ++r) {
                int best = 0; double bv = -INFINITY;
                for (int g = 0; g < NG; ++g) {
                    if (keep & (1u << g)) continue;
                    if (gmax[g] > bv) { bv = gmax[g]; best = g; }
                }
                keep |= 1u << best;
            }
            double tv[TOPK]; int ti[TOPK];
            for (int r = 0; r < TOPK; ++r) { tv[r] = -INFINITY; ti[r] = NE; }
            for (int g = 0; g < NG; ++g) {
                if (!(keep & (1u << g))) continue;
                for (int q = 0; q < GSZ; ++q) {
                    const int ee = g * GSZ + q;
                    const double v = sc[ee];
                    if (v > tv[TOPK - 1]) {
                        int p = TOPK - 1;
                        while (p > 0 && v > tv[p - 1]) {
                            tv[p] = tv[p - 1]; ti[p] = ti[p - 1]; --p;
                        }
                        tv[p] = v; ti[p] = ee;
                    }
                }
            }
            const int base = t * TOPK;
            for (int r = 0; r < TOPK; ++r) {
                out_vals[base + r] = (float)(tv[r] * (double)RSCALE);
                out_idx[base + r]  = (float)ti[r];
            }
        }
    }
}

extern "C" void kernel_launch(void* const* d_in, const int* in_sizes, int n_in,
                              void* d_out, int out_size, void* d_ws, size_t ws_size,
                              hipStream_t stream) {
    const float* x     = (const float*)d_in[0];
    const float* w1    = (const float*)d_in[1];
    const float* b_lin = (const float*)d_in[2];
    const float* bias  = (const float*)d_in[3];
    float* out_vals = (float*)d_out;
    float* out_idx  = (float*)d_out + (size_t)NTOK * TOPK;

    int* wsI = (int*)d_ws;
    unsigned int* wt = (unsigned int*)((char*)d_ws + WOFF);

    hipMemsetAsync(d_ws, 0, 16, stream);
    wsplit_kernel<<<dim3(512), 256, 0, stream>>>(w1, wt);
    router_pass1<<<dim3(NTOK / BT), THREADS, 0, stream>>>(
        x, wt, b_lin, bias, out_vals, out_idx, wsI);
    router_pass2<<<dim3(256), 256, 0, stream>>>(
        x, w1, b_lin, bias, out_vals, out_idx, (const int*)d_ws);
}

// Round 13
// 261.967 us; speedup vs baseline: 1.2397x; 1.2397x over previous
//
#include <hip/hip_runtime.h>
#include <math.h>

#define NTOK   32768
#define DIM    2048
#define NE     256
#define NG     8
#define GSZ    32
#define NLIM   4
#define TOPK   8
#define RSCALE 2.5f
#define TAU    4e-7f

#define BT      32
#define THREADS 256
#define KT      16
#define NKT     (DIM / KT)        // 128
#define WOFF    262144            // wt at d_ws + 256 KB
#define TILE_B  16384             // one wt k-tile: [plane][khalf][256e]*16B

typedef __bf16 bf16x8 __attribute__((ext_vector_type(8)));
typedef float  f32x16 __attribute__((ext_vector_type(16)));

// ---------------------------------------------------------------------------
// Prekernel: split w1 into 2 bf16 planes, layout per 16-k tile (16 KB):
// cell g = ((kt*2+p)*2+hi)*256+e holds w1[e][kt*16+hi*8 .. +8), plane p.
// ---------------------------------------------------------------------------
__global__ __launch_bounds__(256) void wsplit_kernel(
    const float* __restrict__ w1, unsigned int* __restrict__ wt)
{
    const int g  = blockIdx.x * 256 + threadIdx.x;    // [0, 131072)
    const int e  = g & 255;
    const int hi = (g >> 8) & 1;
    const int p  = (g >> 9) & 1;
    const int kt = g >> 10;
    const float* src = w1 + (size_t)e * DIM + kt * 16 + hi * 8;

    uint4 o;
    unsigned int w[4];
#pragma unroll
    for (int q = 0; q < 4; ++q) {
        const float v0 = src[2 * q], v1 = src[2 * q + 1];
        const unsigned int u0 = __float_as_uint(v0);
        const unsigned int u1 = __float_as_uint(v1);
        if (p == 0) {
            w[q] = (u0 >> 16) | (u1 & 0xFFFF0000u);
        } else {
            const float r0 = v0 - __uint_as_float(u0 & 0xFFFF0000u);
            const float r1 = v1 - __uint_as_float(u1 & 0xFFFF0000u);
            w[q] = (__float_as_uint(r0) >> 16) |
                   (__float_as_uint(r1) & 0xFFFF0000u);
        }
    }
    o.x = w[0]; o.y = w[1]; o.z = w[2]; o.w = w[3];
    *(uint4*)(wt + (size_t)g * 4) = o;
}

// ---------------------------------------------------------------------------
// Pass 1: 2-plane / 3-pass bf16 MFMA GEMM. 32 tok x 256 exp per block,
// 4 waves, grid 1024 => 4 blocks/CU. B direct global->register from L2.
// A via LDS xs tile in FRAGMENT-LINEAR layout [buf][plane][hi][tok][16B]:
// read = consecutive lane -> consecutive 16B cell (bank-sequential,
// conflict-free b128); write covers banks 0..31 once per hi-half (2-way
// between halves = free). This is the single change vs round 11 (which had
// 5.9e7 bank conflicts from the stride-32B layout).
// ---------------------------------------------------------------------------
__global__ __launch_bounds__(THREADS, 4) void router_pass1(
    const float* __restrict__ x, const unsigned int* __restrict__ wt,
    const float* __restrict__ b_lin, const float* __restrict__ bias,
    float* __restrict__ out_vals, float* __restrict__ out_idx,
    int* __restrict__ wsI)
{
    __shared__ union {
        unsigned char xs[2][2][2][32][16];   // 4 KB: [buf][plane][hi][tok][16B]
        float sc[32 * 260];                  // 33.3 KB logits (epilogue)
    } sm;

    const int tid  = threadIdx.x;
    const int lane = tid & 63;
    const int wn   = tid >> 6;        // wave = expert quarter (0..3)
    const int l31  = lane & 31;
    const int hi   = lane >> 5;
    const int t0   = blockIdx.x * BT;

    // x staging identity: token xtok = tid>>3, k-pair xk2 = tid&7 (2 floats)
    const int xtok = tid >> 3, xk2 = tid & 7;
    const int xhi = xk2 >> 2, xw = xk2 & 3;
    const float2* xg = (const float2*)(x + (size_t)(t0 + xtok) * DIM) + xk2;

    // per-lane B fragment base: e = wn*64 + ni*32 + l31, k-half = hi, plane p
    const char* wb = (const char*)wt + hi * 4096 + (wn * 64 + l31) * 16;

    auto LOADB = [&](bf16x8 B[2][2], int kt) {   // B[ni][p]
#pragma unroll
        for (int ni = 0; ni < 2; ++ni)
#pragma unroll
            for (int p = 0; p < 2; ++p)
                B[ni][p] = *(const bf16x8*)(wb + (size_t)kt * TILE_B +
                                            ni * 512 + p * 8192);
    };
    // split 2 fp32 -> bf16 h/r pairs, write to xs[b] (fragment-linear)
    auto XWRITE = [&](int b, float2 v) {
        const unsigned int u0 = __float_as_uint(v.x);
        const unsigned int u1 = __float_as_uint(v.y);
        const unsigned int hp = (u0 >> 16) | (u1 & 0xFFFF0000u);
        const float r0 = v.x - __uint_as_float(u0 & 0xFFFF0000u);
        const float r1 = v.y - __uint_as_float(u1 & 0xFFFF0000u);
        const unsigned int rp = (__float_as_uint(r0) >> 16) |
                                (__float_as_uint(r1) & 0xFFFF0000u);
        *(unsigned int*)&sm.xs[b][0][xhi][xtok][xw * 4] = hp;
        *(unsigned int*)&sm.xs[b][1][xhi][xtok][xw * 4] = rp;
    };

    f32x16 acc[2] = {};

    auto COMP = [&](bf16x8 B[2][2], int cur) {
        bf16x8 ah = *(const bf16x8*)&sm.xs[cur][0][hi][l31][0];
        bf16x8 ar = *(const bf16x8*)&sm.xs[cur][1][hi][l31][0];
#pragma unroll
        for (int ni = 0; ni < 2; ++ni) {
            acc[ni] = __builtin_amdgcn_mfma_f32_32x32x16_bf16(ah, B[ni][0], acc[ni], 0, 0, 0);
            acc[ni] = __builtin_amdgcn_mfma_f32_32x32x16_bf16(ah, B[ni][1], acc[ni], 0, 0, 0);
            acc[ni] = __builtin_amdgcn_mfma_f32_32x32x16_bf16(ar, B[ni][0], acc[ni], 0, 0, 0);
        }
    };
    auto BARRIER = [&]() {
        __builtin_amdgcn_sched_barrier(0);
        asm volatile("s_waitcnt lgkmcnt(0)");
        __builtin_amdgcn_sched_barrier(0);
        __builtin_amdgcn_s_barrier();
        __builtin_amdgcn_sched_barrier(0);
    };

    bf16x8 BA[2][2], BB[2][2];
    float2 xo, xe;

    // prologue: B(0), B(1) in regs; xs[0] written; x(1) in xo
    LOADB(BA, 0);
    float2 xv = xg[0];
    XWRITE(0, xv);
    LOADB(BB, 1);
    xo = xg[8];
    BARRIER();

    for (int kt = 0; kt < NKT; kt += 2) {
        // ---- even tile kt: compute BA from xs[0] ----
        if (kt + 1 < NKT) XWRITE(1, xo);
        if (kt + 2 < NKT) xe = xg[(kt + 2) * 8];
        COMP(BA, 0);
        if (kt + 2 < NKT) LOADB(BA, kt + 2);
        BARRIER();
        // ---- odd tile kt+1: compute BB from xs[1] ----
        if (kt + 2 < NKT) XWRITE(0, xe);
        if (kt + 3 < NKT) xo = xg[(kt + 3) * 8];
        COMP(BB, 1);
        if (kt + 3 < NKT) LOADB(BB, kt + 3);
        BARRIER();
    }

    __syncthreads();   // full drain once; LDS reused as sc

    // ---- routing epilogue: 32 tokens ----
    const int tx = tid & 31;
    const int ty = tid >> 5;          // 0..7
    float blv[8], bsv[8];
#pragma unroll
    for (int j = 0; j < 8; ++j) {
        blv[j] = b_lin[tx + 32 * j];
        bsv[j] = bias[tx + 32 * j];
    }

#pragma unroll
    for (int ni = 0; ni < 2; ++ni) {
#pragma unroll
        for (int r = 0; r < 16; ++r) {
            const int row = (r & 3) + 8 * (r >> 2) + 4 * hi;
            const int e   = wn * 64 + ni * 32 + l31;
            sm.sc[row * 260 + e] = acc[ni][r];
        }
    }
    __syncthreads();

#pragma unroll
    for (int i = 0; i < 4; ++i) {
        const int row = ty * 4 + i;
        float s8[8];
        float psum = 0.0f;
#pragma unroll
        for (int j = 0; j < 8; ++j) {
            const float lg = sm.sc[row * 260 + tx + 32 * j] + blv[j];
            const float s = 1.0f / (1.0f + expf(-lg));
            s8[j] = s;
            psum += s;
        }
#pragma unroll
        for (int m = 1; m <= 16; m <<= 1) psum += __shfl_xor(psum, m);
#pragma unroll
        for (int j = 0; j < 8; ++j) s8[j] = s8[j] / psum + bsv[j];

        float gm[8];
#pragma unroll
        for (int j = 0; j < 8; ++j) gm[j] = s8[j];
#pragma unroll
        for (int m = 1; m <= 16; m <<= 1)
#pragma unroll
            for (int j = 0; j < 8; ++j)
                gm[j] = fmaxf(gm[j], __shfl_xor(gm[j], m));

        unsigned keep = 0u;
        float g4v = 0.0f, g5v = 0.0f;
#pragma unroll
        for (int r = 0; r < 5; ++r) {
            float bv = -1e30f; int bg = 0;
#pragma unroll
            for (int g = 0; g < 8; ++g)
                if (!((keep >> g) & 1) && gm[g] > bv) { bv = gm[g]; bg = g; }
            if (r < 4) { keep |= 1u << bg; g4v = bv; }
            else g5v = bv;
        }
        float margin = g4v - g5v;

#pragma unroll
        for (int j = 0; j < 8; ++j)
            if (!((keep >> j) & 1)) s8[j] = -1e30f;

        float tv[9]; int te[9];
#pragma unroll
        for (int r = 0; r < 9; ++r) {
            float bv = -1e30f; int bj = 8;
#pragma unroll
            for (int j = 0; j < 8; ++j)
                if (s8[j] > bv) { bv = s8[j]; bj = j; }
            int be = (bj < 8) ? (tx + 32 * bj) : 9999;
#pragma unroll
            for (int m = 1; m <= 16; m <<= 1) {
                const float ov = __shfl_xor(bv, m);
                const int   oe = __shfl_xor(be, m);
                if (ov > bv || (ov == bv && oe < be)) { bv = ov; be = oe; }
            }
            tv[r] = bv; te[r] = be;
            if (r < 8 && (be & 31) == tx) s8[be >> 5] = -1e30f;
        }
#pragma unroll
        for (int r = 0; r < 8; ++r) margin = fminf(margin, tv[r] - tv[r + 1]);

        if (tx == 0) {
            const int t = t0 + row;
            const int base = t * TOPK;
#pragma unroll
            for (int r = 0; r < 8; ++r) {
                out_vals[base + r] = tv[r] * RSCALE;
                out_idx[base + r]  = (float)te[r];
            }
            if (margin < TAU) {
                const int slot = atomicAdd(&wsI[0], 1);
                if (slot < 60000) wsI[4 + slot] = t;
            }
        }
    }
}

// ---------------------------------------------------------------------------
// Pass 2: exact fp64 recompute + reroute for margin-flagged tokens.
// ---------------------------------------------------------------------------
__global__ __launch_bounds__(256, 1) void router_pass2(
    const float* __restrict__ x, const float* __restrict__ w1,
    const float* __restrict__ b_lin, const float* __restrict__ bias,
    float* __restrict__ out_vals, float* __restrict__ out_idx,
    const int* __restrict__ wsI)
{
    __shared__ double xrow[DIM];
    __shared__ double red[256];
    __shared__ double sc[NE];

    const int tid = threadIdx.x;
    const int count = min(wsI[0], 60000);
    const int* list = wsI + 4;
    const float4* x4 = (const float4*)x;
    const float4* w4 = (const float4*)w1;

    for (int li = blockIdx.x; li < count; li += gridDim.x) {
        const int t = list[li];
        __syncthreads();
#pragma unroll
        for (int q = 0; q < 2; ++q) {
            const int id = tid + 256 * q;
            const float4 v = x4[t * 512 + id];
            xrow[id * 4 + 0] = (double)v.x;
            xrow[id * 4 + 1] = (double)v.y;
            xrow[id * 4 + 2] = (double)v.z;
            xrow[id * 4 + 3] = (double)v.w;
        }
        __syncthreads();

        const int e = tid;
        double a0 = 0.0, a1 = 0.0, a2 = 0.0, a3 = 0.0;
#pragma unroll 2
        for (int k4 = 0; k4 < 512; k4 += 4) {
#pragma unroll
            for (int z = 0; z < 4; ++z) {
                const float4 wv = w4[e * 512 + k4 + z];
                double* ac = (z == 0) ? &a0 : (z == 1) ? &a1 : (z == 2) ? &a2 : &a3;
                *ac = fma(xrow[(k4 + z) * 4 + 0], (double)wv.x, *ac);
                *ac = fma(xrow[(k4 + z) * 4 + 1], (double)wv.y, *ac);
                *ac = fma(xrow[(k4 + z) * 4 + 2], (double)wv.z, *ac);
                *ac = fma(xrow[(k4 + z) * 4 + 3], (double)wv.w, *ac);
            }
        }
        const double lg = ((a0 + a1) + (a2 + a3)) + (double)b_lin[e];
        const double s = 1.0 / (1.0 + exp(-lg));
        red[tid] = s;
        __syncthreads();
        for (int off = 128; off > 0; off >>= 1) {
            if (tid < off) red[tid] += red[tid + off];
            __syncthreads();
        }
        sc[e] = s / red[0] + (double)bias[e];
        __syncthreads();

        if (tid == 0) {
            double gmax[NG];
            for (int g = 0; g < NG; ++g) {
                double mx = -INFINITY;
                for (int q = 0; q < GSZ; ++q) {
                    const double v = sc[g * GSZ + q];
                    mx = (v > mx) ? v : mx;
                }
                gmax[g] = mx;
            }
            unsigned keep = 0u;
            for (int r = 0; r < NLIM; ++r) {
                int best = 0; double bv = -INFINITY;
                for (int g = 0; g < NG; ++g) {
                    if (keep & (1u << g)) continue;
                    if (gmax[g] > bv) { bv = gmax[g]; best = g; }
                }
                keep |= 1u << best;
            }
            double tv[TOPK]; int ti[TOPK];
            for (int r = 0; r < TOPK; ++r) { tv[r] = -INFINITY; ti[r] = NE; }
            for (int g = 0; g < NG; ++g) {
                if (!(keep & (1u << g))) continue;
                for (int q = 0; q < GSZ; ++q) {
                    const int ee = g * GSZ + q;
                    const double v = sc[ee];
                    if (v > tv[TOPK - 1]) {
                        int p = TOPK - 1;
                        while (p > 0 && v > tv[p - 1]) {
                            tv[p] = tv[p - 1]; ti[p] = ti[p - 1]; --p;
                        }
                        tv[p] = v; ti[p] = ee;
                    }
                }
            }
            const int base = t * TOPK;
            for (int r = 0; r < TOPK; ++r) {
                out_vals[base + r] = (float)(tv[r] * (double)RSCALE);
                out_idx[base + r]  = (float)ti[r];
            }
        }
    }
}

extern "C" void kernel_launch(void* const* d_in, const int* in_sizes, int n_in,
                              void* d_out, int out_size, void* d_ws, size_t ws_size,
                              hipStream_t stream) {
    const float* x     = (const float*)d_in[0];
    const float* w1    = (const float*)d_in[1];
    const float* b_lin = (const float*)d_in[2];
    const float* bias  = (const float*)d_in[3];
    float* out_vals = (float*)d_out;
    float* out_idx  = (float*)d_out + (size_t)NTOK * TOPK;

    int* wsI = (int*)d_ws;
    unsigned int* wt = (unsigned int*)((char*)d_ws + WOFF);

    hipMemsetAsync(d_ws, 0, 16, stream);
    wsplit_kernel<<<dim3(512), 256, 0, stream>>>(w1, wt);
    router_pass1<<<dim3(NTOK / BT), THREADS, 0, stream>>>(
        x, wt, b_lin, bias, out_vals, out_idx, wsI);
    router_pass2<<<dim3(256), 256, 0, stream>>>(
        x, w1, b_lin, bias, out_vals, out_idx, (const int*)d_ws);
}